// Round 13
// baseline (447.702 us; speedup 1.0000x reference)
//
#include <hip/hip_runtime.h>
#include <math.h>

#define F 32
#define K 16
#define EPSN 1e-8f
#define NPB 512   // nodes per block (8 iterations of 64)

// Round-13: asm vmcnt-ledger pipeline (round 11) + __launch_bounds__(256,2)
// (empirical 128-VGPR budget, measured rounds 5/10).
// Round 12 failed correctness (absmax 0.898) because WITHOUT the budget the
// allocator targeted ~64 regs and SPILLED in-flight asm-load destinations —
// the waitcnt pass doesn't model INLINEASM defs as vmem, so spill stores
// read the register before the load landed. Forced-live ~93-100 < 128.
//
// Steady iteration t (issue order / ledger):
//   a : issue G1(t)        (C1 ops)   addrs from idx(t)  [arrived: prev KD wait]
//   a5: issue idx(t+2)     (NI ops)   into idx(t)'s regs (dead after a; node copied)
//   b : vmcnt(C1+NI)  -> G0(t) + stores(t-1) + idx(t+1) retired
//   c : issue G0(t+1)      (C0 ops)   addrs from idx(t+1)
//   d : vmcnt(C0)     -> G1(t) + idx(t+2) retired; G0(t+1) stays in flight
//   e : stores(t)          (4 ops)
// vmcnt never drains to 0 in the steady loop. Tail waves that skip stores
// only weaken the waits: harmless.
//
// MFMA formulation (verified round 8): per slab r,
// scores(16k x 16n) += W_r(16x32) . X_r(32x16) via mfma_f32_16x16x32_f16,
// hi/lo split x3 for precision. Lane l: node jcol=l&15, k-quartet kq=l>>4.

typedef _Float16 half8 __attribute__((ext_vector_type(8)));
typedef float f32x4  __attribute__((ext_vector_type(4)));
typedef int   i32x2  __attribute__((ext_vector_type(2)));
typedef int   i32x4  __attribute__((ext_vector_type(4)));

#define VMWAIT(N) do { asm volatile("s_waitcnt vmcnt(%0)" :: "n"(N) : "memory"); \
                       __builtin_amdgcn_sched_barrier(0); } while (0)

__device__ __forceinline__ void gpair(f32x4& a, f32x4& b, const float* x,
                                      unsigned row, int kq) {
    const unsigned off = row * 128u + (unsigned)kq * 32u;
    asm volatile("global_load_dwordx4 %0, %1, %2"
                 : "=&v"(a) : "v"(off), "s"(x) : "memory");
    asm volatile("global_load_dwordx4 %0, %1, %2 offset:16"
                 : "=&v"(b) : "v"(off), "s"(x) : "memory");
}

__device__ __forceinline__ void gstore(float* out, unsigned off, f32x4 v) {
    asm volatile("global_store_dwordx4 %0, %1, %2"
                 :: "v"(off), "v"(v), "s"(out) : "memory");
}

template<int DEG> struct Idx;
template<> struct Idx<1> { int node; int n0;
    __device__ __forceinline__ int nb(int) const { return n0; } };
template<> struct Idx<2> { int node; i32x2 nn;
    __device__ __forceinline__ int nb(int j) const { return nn[j]; } };
template<> struct Idx<3> { int node; i32x2 nn; int n2;
    __device__ __forceinline__ int nb(int j) const { return j < 2 ? nn[j] : n2; } };
template<> struct Idx<4> { int node; i32x4 nn;
    __device__ __forceinline__ int nb(int j) const { return nn[j]; } };

template<int DEG>
__device__ __forceinline__ void load_idx(Idx<DEG>& d, const int* sel,
                                         const int* nei, int ic) {
    const unsigned so = (unsigned)ic << 2;
    asm volatile("global_load_dword %0, %1, %2"
                 : "=&v"(d.node) : "v"(so), "s"(sel) : "memory");
    const unsigned no = (unsigned)(ic * DEG) << 2;
    if constexpr (DEG == 1)
        asm volatile("global_load_dword %0, %1, %2"
                     : "=&v"(d.n0) : "v"(no), "s"(nei) : "memory");
    else if constexpr (DEG == 2)
        asm volatile("global_load_dwordx2 %0, %1, %2"
                     : "=&v"(d.nn) : "v"(no), "s"(nei) : "memory");
    else if constexpr (DEG == 3) {
        asm volatile("global_load_dwordx2 %0, %1, %2"
                     : "=&v"(d.nn) : "v"(no), "s"(nei) : "memory");
        asm volatile("global_load_dword %0, %1, %2 offset:8"
                     : "=&v"(d.n2) : "v"(no), "s"(nei) : "memory");
    } else
        asm volatile("global_load_dwordx4 %0, %1, %2"
                     : "=&v"(d.nn) : "v"(no), "s"(nei) : "memory");
}

template<int DEG>
__device__ __forceinline__ f32x4 slab_compute(f32x4 a, f32x4 b, f32x4 acc,
                                              const _Float16* sWh,
                                              const _Float16* sWl,
                                              int lane, int r) {
    float ss = a[0]*a[0] + a[1]*a[1] + a[2]*a[2] + a[3]*a[3]
             + b[0]*b[0] + b[1]*b[1] + b[2]*b[2] + b[3]*b[3];
    ss += __shfl_xor(ss, 16);     // slice-mates l^16, l^32 share a node
    ss += __shfl_xor(ss, 32);
    float sc = 1.f / (sqrtf(ss) + EPSN);
    if (r > 0) sc *= (1.f / (float)DEG);
    const float f0 = a[0]*sc, f1 = a[1]*sc, f2 = a[2]*sc, f3 = a[3]*sc;
    const float f4 = b[0]*sc, f5 = b[1]*sc, f6 = b[2]*sc, f7 = b[3]*sc;
    half8 bh, bl;
    bh[0]=(_Float16)f0; bl[0]=(_Float16)(f0-(float)bh[0]);
    bh[1]=(_Float16)f1; bl[1]=(_Float16)(f1-(float)bh[1]);
    bh[2]=(_Float16)f2; bl[2]=(_Float16)(f2-(float)bh[2]);
    bh[3]=(_Float16)f3; bl[3]=(_Float16)(f3-(float)bh[3]);
    bh[4]=(_Float16)f4; bl[4]=(_Float16)(f4-(float)bh[4]);
    bh[5]=(_Float16)f5; bl[5]=(_Float16)(f5-(float)bh[5]);
    bh[6]=(_Float16)f6; bl[6]=(_Float16)(f6-(float)bh[6]);
    bh[7]=(_Float16)f7; bl[7]=(_Float16)(f7-(float)bh[7]);
    const int aoff = r * 512 + lane * 8;
    const half8 ah = *(const half8*)(sWh + aoff);
    const half8 al = *(const half8*)(sWl + aoff);
    acc = __builtin_amdgcn_mfma_f32_16x16x32_f16(ah, bh, acc, 0, 0, 0);
    acc = __builtin_amdgcn_mfma_f32_16x16x32_f16(ah, bl, acc, 0, 0, 0);
    acc = __builtin_amdgcn_mfma_f32_16x16x32_f16(al, bh, acc, 0, 0, 0);
    return acc;
}

template<int DEG>
__device__ __forceinline__ void process_deg(const float* __restrict__ x,
                                            const int*   __restrict__ sel,
                                            const int*   __restrict__ nei,
                                            const float* __restrict__ Wf,
                                            const float* __restrict__ Wn,
                                            float* __restrict__ out,
                                            int nd, int i0,
                                            _Float16* sWh, _Float16* sWl)
{
    constexpr int R  = DEG + 1;
    constexpr int H  = (DEG <= 2) ? 1 : 2;        // G0 slab count
    constexpr int C0 = 2 * H;                     // G0 load ops
    constexpr int C1 = 2 * (R - H);               // G1 load ops
    constexpr int NI = (DEG == 3) ? 3 : 2;        // idx load ops
    constexpr int KB = C1 + NI;                   // step-b wait
    constexpr int KD = C0;                        // step-d wait
    constexpr int NW = K * R;
    constexpr int ITERS = NPB / 64;
    const int tid = threadIdx.x;

    // ---- W preamble (C++ vmem; fully drained before the loop) ----
    if (tid < NW) {
        const float* src = (tid < K) ? (Wf + tid * F) : (Wn + (tid - K) * F);
        float ss = 0.f;
        #pragma unroll
        for (int f = 0; f < F; ++f) { const float t = src[f]; ss += t * t; }
        const float sc = 1.f / (sqrtf(ss) + EPSN);
        const int t = tid - K;
        const int r = (tid < K) ? 0   : (1 + t % DEG);
        const int k = (tid < K) ? tid : (t / DEG);
        #pragma unroll
        for (int f = 0; f < F; ++f) {
            const float wv = src[f] * sc;
            const _Float16 hi = (_Float16)wv;
            const _Float16 lo = (_Float16)(wv - (float)hi);
            const int off = r * 512 + (k + 16 * (f >> 3)) * 8 + (f & 7);
            sWh[off] = hi; sWl[off] = lo;
        }
    }
    __syncthreads();

    const int lane = tid & 63;
    const int wv   = tid >> 6;
    const int jcol = lane & 15;
    const int kq   = lane >> 4;
    const int i0w  = i0 + wv * 16 + jcol;

    f32x4 g0[2 * H], g1[2 * (R - H)];
    const f32x4 zed = {0.f, 0.f, 0.f, 0.f};

    Idx<DEG> ix, iy;                        // idx(t) / idx(t+1) ping-pong
    { const int ic = (i0w < nd) ? i0w : (nd - 1);
      load_idx<DEG>(ix, sel, nei, ic); }
    { const int i1 = i0w + 64; const int ic = (i1 < nd) ? i1 : (nd - 1);
      load_idx<DEG>(iy, sel, nei, ic); }
    VMWAIT(NI);                             // idx(0) arrived (NI ops after it)
    #pragma unroll
    for (int r = 0; r < H; ++r)             // issue G0(0)
        gpair(g0[2*r], g0[2*r+1], x,
              (unsigned)((r == 0) ? ix.node : ix.nb(r-1)), kq);

#define ITER(T, XC, YN)                                                        \
    {                                                                          \
        const int nodeT = XC.node;                                             \
        _Pragma("unroll")                                                      \
        for (int r = H; r < R; ++r)          /* a: issue G1(t) */              \
            gpair(g1[2*(r-H)], g1[2*(r-H)+1], x, (unsigned)XC.nb(r-1), kq);    \
        { const int ii = i0w + ((T) + 2) * 64;      /* a5: idx(t+2) -> XC */   \
          load_idx<DEG>(XC, sel, nei, (ii < nd) ? ii : (nd - 1)); }            \
        VMWAIT(KB);                          /* b: G0(t), idx(t+1) arrived */  \
        f32x4 acc = {0.f, 0.f, 0.f, 0.f};                                      \
        _Pragma("unroll")                                                      \
        for (int r = 0; r < H; ++r)                                            \
            acc = slab_compute<DEG>(g0[2*r], g0[2*r+1], acc, sWh, sWl, lane, r);\
        _Pragma("unroll")                                                      \
        for (int r = 0; r < H; ++r)          /* c: issue G0(t+1) */            \
            gpair(g0[2*r], g0[2*r+1], x,                                       \
                  (unsigned)((r == 0) ? YN.node : YN.nb(r-1)), kq);            \
        VMWAIT(KD);                          /* d: G1(t) arrived */            \
        _Pragma("unroll")                                                      \
        for (int r = H; r < R; ++r)                                            \
            acc = slab_compute<DEG>(g1[2*(r-H)], g1[2*(r-H)+1], acc,           \
                                    sWh, sWl, lane, r);                        \
        if (i0w + (T) * 64 < nd) {           /* e: stores(t) */                \
            const unsigned ob = (unsigned)nodeT * 256u + (unsigned)kq * 16u;   \
            _Pragma("unroll")                                                  \
            for (int b = 0; b < 4; ++b)                                        \
                gstore(out, ob + (unsigned)b * 64u,                            \
                       (b == DEG - 1) ? acc : zed);                            \
        }                                                                      \
    }

    #pragma unroll 1
    for (int tp = 0; tp < ITERS; tp += 2) {
        ITER(tp,     ix, iy);
        ITER(tp + 1, iy, ix);
    }
#undef ITER
    VMWAIT(0);
}

struct Args {
    const float* x;
    const int*   sel[4];
    const int*   nei[4];
    const float* Wf[4];
    const float* Wn[4];
    int nd[4];
    int bcum[4];
};

// (256,2) == empirical 128-VGPR budget (measured rounds 5/10). REQUIRED for
// the asm pipeline: without it the allocator spills in-flight asm-load
// destinations (round 12's absmax 0.898). Forced-live ~93-100 < 128.
__global__ __launch_bounds__(256, 2)
void fused_kernel(Args a, float* __restrict__ out)
{
    __shared__ __align__(16) _Float16 sWh[5 * 512];
    __shared__ __align__(16) _Float16 sWl[5 * 512];
    const int bid = blockIdx.x;

    if (bid < a.bcum[0]) {
        process_deg<1>(a.x, a.sel[0], a.nei[0], a.Wf[0], a.Wn[0], out,
                       a.nd[0], bid * NPB, sWh, sWl);
    } else if (bid < a.bcum[1]) {
        process_deg<2>(a.x, a.sel[1], a.nei[1], a.Wf[1], a.Wn[1], out,
                       a.nd[1], (bid - a.bcum[0]) * NPB, sWh, sWl);
    } else if (bid < a.bcum[2]) {
        process_deg<3>(a.x, a.sel[2], a.nei[2], a.Wf[2], a.Wn[2], out,
                       a.nd[2], (bid - a.bcum[1]) * NPB, sWh, sWl);
    } else {
        process_deg<4>(a.x, a.sel[3], a.nei[3], a.Wf[3], a.Wn[3], out,
                       a.nd[3], (bid - a.bcum[2]) * NPB, sWh, sWl);
    }
}

extern "C" void kernel_launch(void* const* d_in, const int* in_sizes, int n_in,
                              void* d_out, int out_size, void* d_ws, size_t ws_size,
                              hipStream_t stream)
{
    Args a;
    a.x = (const float*)d_in[0];
    for (int d = 0; d < 4; ++d) {
        a.sel[d] = (const int*)  d_in[1 + 4 * d];
        a.nei[d] = (const int*)  d_in[2 + 4 * d];
        a.Wf[d]  = (const float*)d_in[3 + 4 * d];
        a.Wn[d]  = (const float*)d_in[4 + 4 * d];
        a.nd[d]  = in_sizes[1 + 4 * d];
    }
    int cum = 0;
    for (int d = 0; d < 4; ++d) {
        cum += (a.nd[d] + NPB - 1) / NPB;
        a.bcum[d] = cum;
    }
    float* out = (float*)d_out;
    fused_kernel<<<cum, 256, 0, stream>>>(a, out);
}